// Round 6
// baseline (234.047 us; speedup 1.0000x reference)
//
#include <hip/hip_runtime.h>

typedef __attribute__((ext_vector_type(8))) short short8;
typedef __attribute__((ext_vector_type(4))) short short4v;
typedef __attribute__((ext_vector_type(4))) float f32x4;
typedef __attribute__((ext_vector_type(2))) unsigned int uint2v;
typedef __attribute__((ext_vector_type(4))) unsigned int uint4v;

#define LOG2E 1.44269504088896340736f

__device__ __forceinline__ float fexp2(float v){ return __builtin_amdgcn_exp2f(v); }
__device__ __forceinline__ float frcp(float v){ return __builtin_amdgcn_rcpf(v); }
__device__ __forceinline__ float silu_f(float v){ return v * frcp(1.0f + fexp2(-v*LOG2E)); }
__device__ __forceinline__ float tanh_f(float v){ return 2.0f*frcp(1.0f+fexp2(-2.0f*LOG2E*v)) - 1.0f; }

__device__ __forceinline__ unsigned short f2bf(float f){
    unsigned int u = __float_as_uint(f);
    u = (u + 0x7FFFu + ((u>>16)&1u)) >> 16;
    return (unsigned short)u;
}
// v_cvt_pk_bf16_f32: lo16 = bf16(a), hi16 = bf16(b)
__device__ __forceinline__ unsigned int cvt_pk(float a, float b){
    unsigned int r;
    asm("v_cvt_pk_bf16_f32 %0, %1, %2" : "=v"(r) : "v"(a), "v"(b));
    return r;
}
__device__ __forceinline__ short4v mk4(unsigned int u0, unsigned int u1){
    uint2v t; t[0] = u0; t[1] = u1;
    return __builtin_bit_cast(short4v, t);
}
__device__ __forceinline__ short8 mk8(unsigned int a, unsigned int b, unsigned int c, unsigned int d){
    uint4v t; t[0] = a; t[1] = b; t[2] = c; t[3] = d;
    return __builtin_bit_cast(short8, t);
}

#define MFMA32(a,b,c) __builtin_amdgcn_mfma_f32_16x16x32_bf16(a,b,c,0,0,0)
#define MFMA16(a,b,c) __builtin_amdgcn_mfma_f32_16x16x16bf16_1k(a,b,c,0,0,0)

// Fragment layouts (validated rounds 2-5):
//  A frag: m=lane&15,  k = KW*(lane>>4)+e   (KW=8 for x32, 4 for x16)
//  B frag: n=lane&15,  k = KW*(lane>>4)+e
//  C frag: n=lane&15,  m = 4*(lane>>4)+r
// => C of one stage feeds B of a 16x16x16 stage with NO cross-lane movement.
//
// Occupancy contract (R5 evidence): allocator uses 100 VGPRs when given a
// generous budget, with zero scratch (WRITE_SIZE == output exactly). 100 fits
// the 128-VGPR/4-wave budget -> pin waves_per_eu(4,4) to double resident
// waves (R5: occupancy 21%, VALUBusy 45% -> latency-bound on 2 waves/EU).
// R3/R4 evidence: an UNpinned allocator targets 6-8 waves, caps at 64-84
// VGPRs, and spills the persistent weight fragments (WRITE 123-299 MB).

__global__ __launch_bounds__(256)
__attribute__((amdgpu_waves_per_eu(4, 4)))
void moe_mfma5_kernel(
    const float* __restrict__ x,
    const float* __restrict__ W1,  const float* __restrict__ b1,
    const float* __restrict__ lng, const float* __restrict__ lnb,
    const float* __restrict__ W2,  const float* __restrict__ b2,
    const float* __restrict__ Wg1, const float* __restrict__ bg1,
    const float* __restrict__ Wg2, const float* __restrict__ bg2,
    const float* __restrict__ We1, const float* __restrict__ be1,
    const float* __restrict__ We2, const float* __restrict__ be2,
    const float* __restrict__ Wh,  const float* __restrict__ bh,
    const float* __restrict__ osc,
    float* __restrict__ out, int B, int niter)
{
    const int tid  = threadIdx.x;
    const int w    = tid >> 6;
    const int lane = tid & 63;
    const int c    = lane & 15;   // batch row within group / A-row m
    const int g    = lane >> 4;   // lane group 0..3

    const long long stride = (long long)gridDim.x * 64;
    long long row0 = (long long)blockIdx.x * 64 + w * 16;

    // ---- prefetch iter 0 (issued before the long init; latency hidden) ----
    f32x4 pf0, pf1, pf2, pf3;
    if (row0 < B) {
        const float* xp = x + (row0 + c) * 64 + 8 * g;
        pf0 = *(const f32x4*)(xp);
        pf1 = *(const f32x4*)(xp + 4);
        pf2 = *(const f32x4*)(xp + 32);
        pf3 = *(const f32x4*)(xp + 36);
    }

    // ================= one-time weight/bias fragment init =================
    // stage1 concat features f: [0,24)=W1, [24,40)=Wg1, [40,43)=Wh, pad to 48
    short8 a1[3][2];
#pragma unroll
    for (int t = 0; t < 3; ++t) {
        const int f = 16 * t + c;
#pragma unroll
        for (int s = 0; s < 2; ++s) {
            short8 r;
#pragma unroll
            for (int e = 0; e < 8; ++e) {
                const int k = 32 * s + 8 * g + e;
                float v = 0.0f;
                if (f < 24)      v = W1[k * 24 + f];
                else if (f < 40) v = Wg1[k * 16 + (f - 24)];
                else if (f < 43) v = Wh[k * 3 + (f - 40)];
                r[e] = (short)f2bf(v);
            }
            a1[t][s] = r;
        }
    }
    // W2 (lng folded into rows), K=24 padded to 32; bias b2' in k==24 slot
    short4v aw[2][2];
#pragma unroll
    for (int t = 0; t < 2; ++t) {
        const int f = 16 * t + c;
        float bfold = 0.0f;
        if (f < 24) {
            bfold = b2[f];
            for (int k = 0; k < 24; ++k) bfold += lnb[k] * W2[k * 24 + f];
        }
#pragma unroll
        for (int s = 0; s < 2; ++s) {
            short4v r;
#pragma unroll
            for (int e = 0; e < 4; ++e) {
                const int k = 16 * s + 4 * g + e;
                float v = (f < 24 && k < 24) ? lng[k] * W2[k * 24 + f] : 0.0f;
                if (s == 1 && g == 2 && e == 0) v = bfold;   // k==24 bias slot
                r[e] = (short)f2bf(v);
            }
            aw[t][s] = r;
        }
    }
    // experts hidden concat m=20*ei+j in [0,60), K=24 pad 32; be1 in k==24 slot
    short4v ae[4][2];
#pragma unroll
    for (int t = 0; t < 4; ++t) {
        const int f  = 16 * t + c;
        const int fc = (f < 60) ? f : 0;
        const int ei = fc / 20, j = fc % 20;
        const float bias = (f < 60) ? be1[f] : 0.0f;
#pragma unroll
        for (int s = 0; s < 2; ++s) {
            short4v r;
#pragma unroll
            for (int e = 0; e < 4; ++e) {
                const int k = 16 * s + 4 * g + e;
                float v = (f < 60 && k < 24) ? We1[(ei * 24 + k) * 20 + j] : 0.0f;
                if (s == 1 && g == 2 && e == 0) v = bias;    // k==24 bias slot
                r[e] = (short)f2bf(v);
            }
            ae[t][s] = r;
        }
    }
    // Final GEMM A: M=3 (output dim o=c), K=64: k<60 -> We2[k/20][k%20][o]*osc[o],
    // k=60..62 -> be2[k-60][o]*osc[o] (gw rides the matching B slots), k=63 -> 0.
    short4v ao[4];
    {
        const float oscv = (c < 3) ? osc[c] : 0.0f;
#pragma unroll
        for (int s = 0; s < 4; ++s) {
            short4v r;
#pragma unroll
            for (int e = 0; e < 4; ++e) {
                const int k = 16 * s + 4 * g + e;
                float v = 0.0f;
                if (c < 3) {
                    if (k < 60) {
                        const int ei = k / 20, j = k % 20;
                        v = We2[(ei * 20 + j) * 3 + c] * oscv;
                    } else if (k < 63) {
                        v = be2[(k - 60) * 3 + c] * oscv;
                    }
                }
                r[e] = (short)f2bf(v);
            }
            ao[s] = r;
        }
    }
    // gate Wg2: K=16 exact
    short4v ag;
#pragma unroll
    for (int e = 0; e < 4; ++e) {
        const int k = 4 * g + e;
        float v = (c < 3) ? Wg2[k * 3 + c] : 0.0f;
        ag[e] = (short)f2bf(v);
    }
    // stage1 biases (K=64 exact, no pad slot available)
    float bs1[3][4];
#pragma unroll
    for (int t = 0; t < 3; ++t)
#pragma unroll
    for (int r = 0; r < 4; ++r) {
        const int m = 16 * t + 4 * g + r;
        float v = 0.0f;
        if (m < 24)      v = b1[m];
        else if (m < 40) v = bg1[m - 24];
        else if (m < 43) v = bh[m - 40];
        bs1[t][r] = v;
    }
    // gate bias: wave-uniform scalars (SGPR), applied via cndmask at C-init
    const float gb0 = bg2[0], gb1 = bg2[1], gb2 = bg2[2];

    const unsigned int ONEBF = 0x00003F80u;  // lo half = bf16(1.0)

    // ================= main loop: one 16-row group per wave per iter =================
    for (int it = 0; it < niter; ++it) {
        if (row0 >= B) break;
        const f32x4 q0 = pf0, q1 = pf1, q2 = pf2, q3 = pf3;
        const long long nrow0 = row0 + stride;
        if (it + 1 < niter && nrow0 < B) {
            const float* np = x + (nrow0 + c) * 64 + 8 * g;
            pf0 = *(const f32x4*)(np);
            pf1 = *(const f32x4*)(np + 4);
            pf2 = *(const f32x4*)(np + 32);
            pf3 = *(const f32x4*)(np + 36);
        }

        const short8 bx0 = mk8(cvt_pk(q0[0],q0[1]), cvt_pk(q0[2],q0[3]),
                               cvt_pk(q1[0],q1[1]), cvt_pk(q1[2],q1[3]));
        const short8 bx1 = mk8(cvt_pk(q2[0],q2[1]), cvt_pk(q2[2],q2[3]),
                               cvt_pk(q3[0],q3[1]), cvt_pk(q3[2],q3[3]));

        // ---- stage 1: 3 M-tiles x K=64 ----
        f32x4 c0 = {bs1[0][0], bs1[0][1], bs1[0][2], bs1[0][3]};
        f32x4 c1 = {bs1[1][0], bs1[1][1], bs1[1][2], bs1[1][3]};
        f32x4 c2 = {bs1[2][0], bs1[2][1], bs1[2][2], bs1[2][3]};
        c0 = MFMA32(a1[0][0], bx0, c0); c0 = MFMA32(a1[0][1], bx1, c0);
        c1 = MFMA32(a1[1][0], bx0, c1); c1 = MFMA32(a1[1][1], bx1, c1);
        c2 = MFMA32(a1[2][0], bx0, c2); c2 = MFMA32(a1[2][1], bx1, c2);

        // ---- gate: send tanh of the tile this lane owns; receive from lane^32 ----
        const f32x4 ts = (g < 2) ? c2 : c1;
        const unsigned int gs0 = cvt_pk(tanh_f(ts[0]), tanh_f(ts[1]));
        const unsigned int gs1 = cvt_pk(tanh_f(ts[2]), tanh_f(ts[3]));
        const unsigned int gr0 = (unsigned int)__shfl_xor((int)gs0, 32, 64);
        const unsigned int gr1 = (unsigned int)__shfl_xor((int)gs1, 32, 64);
        f32x4 cg = { (g == 0) ? gb0 : 0.0f,
                     (g == 0) ? gb1 : 0.0f,
                     (g == 0) ? gb2 : 0.0f, 0.0f };
        cg = MFMA16(ag, mk4(gr0, gr1), cg);

        // ---- silu + LayerNorm (lng/lnb folded into aw / k==24 slot) ----
        const float h00=silu_f(c0[0]), h01=silu_f(c0[1]), h02=silu_f(c0[2]), h03=silu_f(c0[3]);
        const float h10=silu_f(c1[0]), h11=silu_f(c1[1]), h12=silu_f(c1[2]), h13=silu_f(c1[3]);
        float S = h00+h01+h02+h03;
        float Q = h00*h00+h01*h01+h02*h02+h03*h03;
        if (g < 2) { S += h10+h11+h12+h13; Q += h10*h10+h11*h11+h12*h12+h13*h13; }
        S += __shfl_xor(S, 16, 64); S += __shfl_xor(S, 32, 64);
        Q += __shfl_xor(Q, 16, 64); Q += __shfl_xor(Q, 32, 64);
        const float mu = S * (1.0f/24.0f);
        float var = Q * (1.0f/24.0f) - mu*mu; var = fmaxf(var, 0.0f);
        const float inv = __builtin_amdgcn_rsqf(var + 1e-5f);

        const short4v B0 = mk4(cvt_pk((h00-mu)*inv, (h01-mu)*inv),
                               cvt_pk((h02-mu)*inv, (h03-mu)*inv));
        const short4v B1 = (g < 2) ? mk4(cvt_pk((h10-mu)*inv, (h11-mu)*inv),
                                         cvt_pk((h12-mu)*inv, (h13-mu)*inv))
                         : ((g == 2) ? mk4(ONEBF, 0u) : mk4(0u, 0u));

        // ---- stage 2 (C init 0; bias rides k==24 slot) ----
        f32x4 d0 = {0.f,0.f,0.f,0.f}, d1 = {0.f,0.f,0.f,0.f};
        d0 = MFMA16(aw[0][0], B0, d0); d0 = MFMA16(aw[0][1], B1, d0);
        d1 = MFMA16(aw[1][0], B0, d1); d1 = MFMA16(aw[1][1], B1, d1);
        const float j00=silu_f(d0[0]), j01=silu_f(d0[1]), j02=silu_f(d0[2]), j03=silu_f(d0[3]);
        const float j10=silu_f(d1[0]), j11=silu_f(d1[1]), j12=silu_f(d1[2]), j13=silu_f(d1[3]);
        const short4v E0 = mk4(cvt_pk(j00,j01), cvt_pk(j02,j03));
        const short4v E1 = (g < 2) ? mk4(cvt_pk(j10,j11), cvt_pk(j12,j13))
                         : ((g == 2) ? mk4(ONEBF, 0u) : mk4(0u, 0u));

        // ---- experts hidden: 60-feature concat, 4 M-tiles ----
        f32x4 ec0={0.f,0.f,0.f,0.f}, ec1={0.f,0.f,0.f,0.f}, ec2={0.f,0.f,0.f,0.f}, ec3={0.f,0.f,0.f,0.f};
        ec0 = MFMA16(ae[0][0], E0, ec0); ec0 = MFMA16(ae[0][1], E1, ec0);
        ec1 = MFMA16(ae[1][0], E0, ec1); ec1 = MFMA16(ae[1][1], E1, ec1);
        ec2 = MFMA16(ae[2][0], E0, ec2); ec2 = MFMA16(ae[2][1], E1, ec2);
        ec3 = MFMA16(ae[3][0], E0, ec3); ec3 = MFMA16(ae[3][1], E1, ec3);

        // ---- softmax gate weights (logits bounded by tanh: no max-sub needed) ----
        const float l0 = __shfl(cg[0], c, 64);
        const float l1 = __shfl(cg[1], c, 64);
        const float l2 = __shfl(cg[2], c, 64);
        const float x0 = fexp2(l0*LOG2E), x1 = fexp2(l1*LOG2E), x2 = fexp2(l2*LOG2E);
        const float rs = frcp(x0 + x1 + x2);
        const float gw0 = x0*rs, gw1 = x1*rs, gw2 = x2*rs;

        // ---- final GEMM: B = gw[expert(k)]*silu(eh[k]) (k<60), gw vector in pads ----
        // per 4-elt tile, expert index is uniform: t0->e0; t1: g==0->e0 else e1;
        // t2: g<2->e1 else e2; t3: e2 (g==3 overridden by gw pad vector)
        const float gt0 = gw0;
        const float gt1 = (g == 0) ? gw0 : gw1;
        const float gt2 = (g < 2) ? gw1 : gw2;
        const float gt3 = gw2;
        const short4v F0 = mk4(cvt_pk(gt0*silu_f(ec0[0]), gt0*silu_f(ec0[1])),
                               cvt_pk(gt0*silu_f(ec0[2]), gt0*silu_f(ec0[3])));
        const short4v F1 = mk4(cvt_pk(gt1*silu_f(ec1[0]), gt1*silu_f(ec1[1])),
                               cvt_pk(gt1*silu_f(ec1[2]), gt1*silu_f(ec1[3])));
        const short4v F2 = mk4(cvt_pk(gt2*silu_f(ec2[0]), gt2*silu_f(ec2[1])),
                               cvt_pk(gt2*silu_f(ec2[2]), gt2*silu_f(ec2[3])));
        const short4v F3 = (g == 3) ? mk4(cvt_pk(gw0, gw1), cvt_pk(gw2, 0.0f))
                         : mk4(cvt_pk(gt3*silu_f(ec3[0]), gt3*silu_f(ec3[1])),
                               cvt_pk(gt3*silu_f(ec3[2]), gt3*silu_f(ec3[3])));
        f32x4 co = {0.f,0.f,0.f,0.f};
        co = MFMA16(ao[0], F0, co); co = MFMA16(ao[1], F1, co);
        co = MFMA16(ao[2], F2, co); co = MFMA16(ao[3], F3, co);
        // co[r] at g==0 = gated+biased moe output o=r for row c

        // ---- add linear head (lives at g==2 lanes in c2[0..2]) and store ----
        const float lin0 = __shfl(c2[0], 32 + c, 64);
        const float lin1 = __shfl(c2[1], 32 + c, 64);
        const float lin2 = __shfl(c2[2], 32 + c, 64);

        if (g == 0) {
            float* op = out + (row0 + c) * 3;
            op[0] = lin0 + co[0];
            op[1] = lin1 + co[1];
            op[2] = lin2 + co[2];
        }

        row0 = nrow0;
    }
}

extern "C" void kernel_launch(void* const* d_in, const int* in_sizes, int n_in,
                              void* d_out, int out_size, void* d_ws, size_t ws_size,
                              hipStream_t stream) {
    const float* x   = (const float*)d_in[0];
    const float* W1  = (const float*)d_in[1];
    const float* b1  = (const float*)d_in[2];
    const float* lng = (const float*)d_in[3];
    const float* lnb = (const float*)d_in[4];
    const float* W2  = (const float*)d_in[5];
    const float* b2  = (const float*)d_in[6];
    const float* Wg1 = (const float*)d_in[7];
    const float* bg1 = (const float*)d_in[8];
    const float* Wg2 = (const float*)d_in[9];
    const float* bg2 = (const float*)d_in[10];
    const float* We1 = (const float*)d_in[11];
    const float* be1 = (const float*)d_in[12];
    const float* We2 = (const float*)d_in[13];
    const float* be2 = (const float*)d_in[14];
    const float* Wh  = (const float*)d_in[15];
    const float* bh  = (const float*)d_in[16];
    const float* osc = (const float*)d_in[17];
    float* out = (float*)d_out;

    const int B = in_sizes[0] / 64;
    const int G = 4096;
    const long long per = (long long)G * 64;
    const int niter = (int)((B + per - 1) / per);
    moe_mfma5_kernel<<<dim3(G), dim3(256), 0, stream>>>(
        x, W1, b1, lng, lnb, W2, b2, Wg1, bg1, Wg2, bg2,
        We1, be1, We2, be2, Wh, bh, osc, out, B, niter);
}

// Round 7
// 130.059 us; speedup vs baseline: 1.7995x; 1.7995x over previous
//
#include <hip/hip_runtime.h>

typedef __attribute__((ext_vector_type(8))) short short8;
typedef __attribute__((ext_vector_type(4))) short short4v;
typedef __attribute__((ext_vector_type(4))) float f32x4;
typedef __attribute__((ext_vector_type(2))) unsigned int uint2v;
typedef __attribute__((ext_vector_type(4))) unsigned int uint4v;

#define LOG2E 1.44269504088896340736f

__device__ __forceinline__ float fexp2(float v){ return __builtin_amdgcn_exp2f(v); }
__device__ __forceinline__ float frcp(float v){ return __builtin_amdgcn_rcpf(v); }
__device__ __forceinline__ float silu_f(float v){ return v * frcp(1.0f + fexp2(-v*LOG2E)); }
__device__ __forceinline__ float tanh_f(float v){ return 2.0f*frcp(1.0f+fexp2(-2.0f*LOG2E*v)) - 1.0f; }

__device__ __forceinline__ unsigned short f2bf(float f){
    unsigned int u = __float_as_uint(f);
    u = (u + 0x7FFFu + ((u>>16)&1u)) >> 16;
    return (unsigned short)u;
}
// v_cvt_pk_bf16_f32: lo16 = bf16(a), hi16 = bf16(b)
__device__ __forceinline__ unsigned int cvt_pk(float a, float b){
    unsigned int r;
    asm("v_cvt_pk_bf16_f32 %0, %1, %2" : "=v"(r) : "v"(a), "v"(b));
    return r;
}
__device__ __forceinline__ short4v mk4(unsigned int u0, unsigned int u1){
    uint2v t; t[0] = u0; t[1] = u1;
    return __builtin_bit_cast(short4v, t);
}
__device__ __forceinline__ short8 mk8(unsigned int a, unsigned int b, unsigned int c, unsigned int d){
    uint4v t; t[0] = a; t[1] = b; t[2] = c; t[3] = d;
    return __builtin_bit_cast(short8, t);
}

#define MFMA32(a,b,c) __builtin_amdgcn_mfma_f32_16x16x32_bf16(a,b,c,0,0,0)
#define MFMA16(a,b,c) __builtin_amdgcn_mfma_f32_16x16x16bf16_1k(a,b,c,0,0,0)

// Fragment layouts (validated rounds 2-5):
//  A frag: m=lane&15,  k = KW*(lane>>4)+e   (KW=8 for x32, 4 for x16)
//  B frag: n=lane&15,  k = KW*(lane>>4)+e
//  C frag: n=lane&15,  m = 4*(lane>>4)+r
// => C of one stage feeds B of a 16x16x16 stage with NO cross-lane movement.
//
// Occupancy/ILP contract (R4-R6 evidence):
//  - waves_per_eu(2,2): allocator uses ~100 VGPR base, ZERO scratch
//    (WRITE_SIZE == output exactly). Any attempt to raise wave count
//    ((4,4) -> 64 VGPR cap, unpinned -> 64-84 cap) spills the persistent
//    weight fragments: WRITE_SIZE 123-299 MB, dur 234-273 us.
//  - So latency hiding comes from ILP instead: TWO independent 16-row
//    chains per wave per iteration, sharing the weight-fragment registers.

__global__ __launch_bounds__(256)
__attribute__((amdgpu_waves_per_eu(2, 2)))
void moe_mfma6_kernel(
    const float* __restrict__ x,
    const float* __restrict__ W1,  const float* __restrict__ b1,
    const float* __restrict__ lng, const float* __restrict__ lnb,
    const float* __restrict__ W2,  const float* __restrict__ b2,
    const float* __restrict__ Wg1, const float* __restrict__ bg1,
    const float* __restrict__ Wg2, const float* __restrict__ bg2,
    const float* __restrict__ We1, const float* __restrict__ be1,
    const float* __restrict__ We2, const float* __restrict__ be2,
    const float* __restrict__ Wh,  const float* __restrict__ bh,
    const float* __restrict__ osc,
    float* __restrict__ out, int B, int niter)
{
    const int tid  = threadIdx.x;
    const int w    = tid >> 6;
    const int lane = tid & 63;
    const int c    = lane & 15;   // batch row within group / A-row m
    const int g    = lane >> 4;   // lane group 0..3

    const long long stride = (long long)gridDim.x * 128;   // 4 waves x 32 rows
    long long rowA = (long long)blockIdx.x * 128 + w * 32; // chain A base
    // chain B base = rowA + 16

    // ---- prefetch iter 0 for both chains ----
    f32x4 pa0, pa1, pa2, pa3, pb0, pb1, pb2, pb3;
    if (rowA < B) {
        const float* xp = x + (rowA + c) * 64 + 8 * g;
        pa0 = *(const f32x4*)(xp);
        pa1 = *(const f32x4*)(xp + 4);
        pa2 = *(const f32x4*)(xp + 32);
        pa3 = *(const f32x4*)(xp + 36);
    }
    if (rowA + 16 < B) {
        const float* xp = x + (rowA + 16 + c) * 64 + 8 * g;
        pb0 = *(const f32x4*)(xp);
        pb1 = *(const f32x4*)(xp + 4);
        pb2 = *(const f32x4*)(xp + 32);
        pb3 = *(const f32x4*)(xp + 36);
    }

    // ================= one-time weight/bias fragment init =================
    // stage1 concat features f: [0,24)=W1, [24,40)=Wg1, [40,43)=Wh, pad to 48
    short8 a1[3][2];
#pragma unroll
    for (int t = 0; t < 3; ++t) {
        const int f = 16 * t + c;
#pragma unroll
        for (int s = 0; s < 2; ++s) {
            short8 r;
#pragma unroll
            for (int e = 0; e < 8; ++e) {
                const int k = 32 * s + 8 * g + e;
                float v = 0.0f;
                if (f < 24)      v = W1[k * 24 + f];
                else if (f < 40) v = Wg1[k * 16 + (f - 24)];
                else if (f < 43) v = Wh[k * 3 + (f - 40)];
                r[e] = (short)f2bf(v);
            }
            a1[t][s] = r;
        }
    }
    // W2 (lng folded into rows), K=24 padded to 32; bias b2' in k==24 slot
    short4v aw[2][2];
#pragma unroll
    for (int t = 0; t < 2; ++t) {
        const int f = 16 * t + c;
        float bfold = 0.0f;
        if (f < 24) {
            bfold = b2[f];
            for (int k = 0; k < 24; ++k) bfold += lnb[k] * W2[k * 24 + f];
        }
#pragma unroll
        for (int s = 0; s < 2; ++s) {
            short4v r;
#pragma unroll
            for (int e = 0; e < 4; ++e) {
                const int k = 16 * s + 4 * g + e;
                float v = (f < 24 && k < 24) ? lng[k] * W2[k * 24 + f] : 0.0f;
                if (s == 1 && g == 2 && e == 0) v = bfold;   // k==24 bias slot
                r[e] = (short)f2bf(v);
            }
            aw[t][s] = r;
        }
    }
    // experts hidden concat m=20*ei+j in [0,60), K=24 pad 32; be1 in k==24 slot
    short4v ae[4][2];
#pragma unroll
    for (int t = 0; t < 4; ++t) {
        const int f  = 16 * t + c;
        const int fc = (f < 60) ? f : 0;
        const int ei = fc / 20, j = fc % 20;
        const float bias = (f < 60) ? be1[f] : 0.0f;
#pragma unroll
        for (int s = 0; s < 2; ++s) {
            short4v r;
#pragma unroll
            for (int e = 0; e < 4; ++e) {
                const int k = 16 * s + 4 * g + e;
                float v = (f < 60 && k < 24) ? We1[(ei * 24 + k) * 20 + j] : 0.0f;
                if (s == 1 && g == 2 && e == 0) v = bias;    // k==24 bias slot
                r[e] = (short)f2bf(v);
            }
            ae[t][s] = r;
        }
    }
    // Final GEMM A: M=3 (o=c), K=64: k<60 -> We2*osc; k=60..62 -> be2*osc
    short4v ao[4];
    {
        const float oscv = (c < 3) ? osc[c] : 0.0f;
#pragma unroll
        for (int s = 0; s < 4; ++s) {
            short4v r;
#pragma unroll
            for (int e = 0; e < 4; ++e) {
                const int k = 16 * s + 4 * g + e;
                float v = 0.0f;
                if (c < 3) {
                    if (k < 60) {
                        const int ei = k / 20, j = k % 20;
                        v = We2[(ei * 20 + j) * 3 + c] * oscv;
                    } else if (k < 63) {
                        v = be2[(k - 60) * 3 + c] * oscv;
                    }
                }
                r[e] = (short)f2bf(v);
            }
            ao[s] = r;
        }
    }
    // gate Wg2: K=16 exact
    short4v ag;
#pragma unroll
    for (int e = 0; e < 4; ++e) {
        const int k = 4 * g + e;
        float v = (c < 3) ? Wg2[k * 3 + c] : 0.0f;
        ag[e] = (short)f2bf(v);
    }
    // stage1 biases
    float bs1[3][4];
#pragma unroll
    for (int t = 0; t < 3; ++t)
#pragma unroll
    for (int r = 0; r < 4; ++r) {
        const int m = 16 * t + 4 * g + r;
        float v = 0.0f;
        if (m < 24)      v = b1[m];
        else if (m < 40) v = bg1[m - 24];
        else if (m < 43) v = bh[m - 40];
        bs1[t][r] = v;
    }
    const float gb0 = bg2[0], gb1 = bg2[1], gb2 = bg2[2];
    const unsigned int ONEBF = 0x00003F80u;  // lo half = bf16(1.0)

    // ---- per-chain body (inlined twice per iteration; chains share weights,
    //      have no mutual deps -> scheduler interleaves to hide latency) ----
    auto process = [&](long long prow, const f32x4& q0, const f32x4& q1,
                       const f32x4& q2, const f32x4& q3) {
        const short8 bx0 = mk8(cvt_pk(q0[0],q0[1]), cvt_pk(q0[2],q0[3]),
                               cvt_pk(q1[0],q1[1]), cvt_pk(q1[2],q1[3]));
        const short8 bx1 = mk8(cvt_pk(q2[0],q2[1]), cvt_pk(q2[2],q2[3]),
                               cvt_pk(q3[0],q3[1]), cvt_pk(q3[2],q3[3]));

        // stage 1: 3 M-tiles x K=64
        f32x4 c0 = {bs1[0][0], bs1[0][1], bs1[0][2], bs1[0][3]};
        f32x4 c1 = {bs1[1][0], bs1[1][1], bs1[1][2], bs1[1][3]};
        f32x4 c2 = {bs1[2][0], bs1[2][1], bs1[2][2], bs1[2][3]};
        c0 = MFMA32(a1[0][0], bx0, c0); c0 = MFMA32(a1[0][1], bx1, c0);
        c1 = MFMA32(a1[1][0], bx0, c1); c1 = MFMA32(a1[1][1], bx1, c1);
        c2 = MFMA32(a1[2][0], bx0, c2); c2 = MFMA32(a1[2][1], bx1, c2);

        // gate: tanh of owned tile; exchange with lane^32
        const f32x4 ts = (g < 2) ? c2 : c1;
        const unsigned int gs0 = cvt_pk(tanh_f(ts[0]), tanh_f(ts[1]));
        const unsigned int gs1 = cvt_pk(tanh_f(ts[2]), tanh_f(ts[3]));
        const unsigned int gr0 = (unsigned int)__shfl_xor((int)gs0, 32, 64);
        const unsigned int gr1 = (unsigned int)__shfl_xor((int)gs1, 32, 64);
        f32x4 cg = { (g == 0) ? gb0 : 0.0f,
                     (g == 0) ? gb1 : 0.0f,
                     (g == 0) ? gb2 : 0.0f, 0.0f };
        cg = MFMA16(ag, mk4(gr0, gr1), cg);

        // silu + LayerNorm (lng/lnb folded into aw / k==24 slot)
        const float h00=silu_f(c0[0]), h01=silu_f(c0[1]), h02=silu_f(c0[2]), h03=silu_f(c0[3]);
        const float h10=silu_f(c1[0]), h11=silu_f(c1[1]), h12=silu_f(c1[2]), h13=silu_f(c1[3]);
        float S = h00+h01+h02+h03;
        float Q = h00*h00+h01*h01+h02*h02+h03*h03;
        if (g < 2) { S += h10+h11+h12+h13; Q += h10*h10+h11*h11+h12*h12+h13*h13; }
        S += __shfl_xor(S, 16, 64); S += __shfl_xor(S, 32, 64);
        Q += __shfl_xor(Q, 16, 64); Q += __shfl_xor(Q, 32, 64);
        const float mu = S * (1.0f/24.0f);
        float var = Q * (1.0f/24.0f) - mu*mu; var = fmaxf(var, 0.0f);
        const float inv = __builtin_amdgcn_rsqf(var + 1e-5f);

        const short4v B0 = mk4(cvt_pk((h00-mu)*inv, (h01-mu)*inv),
                               cvt_pk((h02-mu)*inv, (h03-mu)*inv));
        const short4v B1 = (g < 2) ? mk4(cvt_pk((h10-mu)*inv, (h11-mu)*inv),
                                         cvt_pk((h12-mu)*inv, (h13-mu)*inv))
                         : ((g == 2) ? mk4(ONEBF, 0u) : mk4(0u, 0u));

        // stage 2 (bias rides k==24 slot)
        f32x4 d0 = {0.f,0.f,0.f,0.f}, d1 = {0.f,0.f,0.f,0.f};
        d0 = MFMA16(aw[0][0], B0, d0); d0 = MFMA16(aw[0][1], B1, d0);
        d1 = MFMA16(aw[1][0], B0, d1); d1 = MFMA16(aw[1][1], B1, d1);
        const float j00=silu_f(d0[0]), j01=silu_f(d0[1]), j02=silu_f(d0[2]), j03=silu_f(d0[3]);
        const float j10=silu_f(d1[0]), j11=silu_f(d1[1]), j12=silu_f(d1[2]), j13=silu_f(d1[3]);
        const short4v E0 = mk4(cvt_pk(j00,j01), cvt_pk(j02,j03));
        const short4v E1 = (g < 2) ? mk4(cvt_pk(j10,j11), cvt_pk(j12,j13))
                         : ((g == 2) ? mk4(ONEBF, 0u) : mk4(0u, 0u));

        // experts hidden: 60-feature concat, 4 M-tiles
        f32x4 ec0={0.f,0.f,0.f,0.f}, ec1={0.f,0.f,0.f,0.f}, ec2={0.f,0.f,0.f,0.f}, ec3={0.f,0.f,0.f,0.f};
        ec0 = MFMA16(ae[0][0], E0, ec0); ec0 = MFMA16(ae[0][1], E1, ec0);
        ec1 = MFMA16(ae[1][0], E0, ec1); ec1 = MFMA16(ae[1][1], E1, ec1);
        ec2 = MFMA16(ae[2][0], E0, ec2); ec2 = MFMA16(ae[2][1], E1, ec2);
        ec3 = MFMA16(ae[3][0], E0, ec3); ec3 = MFMA16(ae[3][1], E1, ec3);

        // softmax gate weights (tanh-bounded logits: no max-sub needed)
        const float l0 = __shfl(cg[0], c, 64);
        const float l1 = __shfl(cg[1], c, 64);
        const float l2 = __shfl(cg[2], c, 64);
        const float x0 = fexp2(l0*LOG2E), x1 = fexp2(l1*LOG2E), x2 = fexp2(l2*LOG2E);
        const float rs = frcp(x0 + x1 + x2);
        const float gw0 = x0*rs, gw1 = x1*rs, gw2 = x2*rs;

        // final GEMM: B = gw[expert(k)]*silu(eh[k]) (k<60), gw vector in pads
        const float gt0 = gw0;
        const float gt1 = (g == 0) ? gw0 : gw1;
        const float gt2 = (g < 2) ? gw1 : gw2;
        const float gt3 = gw2;
        const short4v F0 = mk4(cvt_pk(gt0*silu_f(ec0[0]), gt0*silu_f(ec0[1])),
                               cvt_pk(gt0*silu_f(ec0[2]), gt0*silu_f(ec0[3])));
        const short4v F1 = mk4(cvt_pk(gt1*silu_f(ec1[0]), gt1*silu_f(ec1[1])),
                               cvt_pk(gt1*silu_f(ec1[2]), gt1*silu_f(ec1[3])));
        const short4v F2 = mk4(cvt_pk(gt2*silu_f(ec2[0]), gt2*silu_f(ec2[1])),
                               cvt_pk(gt2*silu_f(ec2[2]), gt2*silu_f(ec2[3])));
        const short4v F3 = (g == 3) ? mk4(cvt_pk(gw0, gw1), cvt_pk(gw2, 0.0f))
                         : mk4(cvt_pk(gt3*silu_f(ec3[0]), gt3*silu_f(ec3[1])),
                               cvt_pk(gt3*silu_f(ec3[2]), gt3*silu_f(ec3[3])));
        f32x4 co = {0.f,0.f,0.f,0.f};
        co = MFMA16(ao[0], F0, co); co = MFMA16(ao[1], F1, co);
        co = MFMA16(ao[2], F2, co); co = MFMA16(ao[3], F3, co);

        // add linear head (g==2 lanes hold it in c2[0..2]) and store
        const float lin0 = __shfl(c2[0], 32 + c, 64);
        const float lin1 = __shfl(c2[1], 32 + c, 64);
        const float lin2 = __shfl(c2[2], 32 + c, 64);

        if (g == 0) {
            float* op = out + (prow + c) * 3;
            op[0] = lin0 + co[0];
            op[1] = lin1 + co[1];
            op[2] = lin2 + co[2];
        }
    };

    // ================= main loop: two 16-row chains per wave per iter =================
    for (int it = 0; it < niter; ++it) {
        if (rowA >= B) break;
        const f32x4 qa0 = pa0, qa1 = pa1, qa2 = pa2, qa3 = pa3;
        const f32x4 qb0 = pb0, qb1 = pb1, qb2 = pb2, qb3 = pb3;
        const long long curA = rowA;
        const long long nrowA = rowA + stride;
        if (it + 1 < niter) {
            if (nrowA < B) {
                const float* np = x + (nrowA + c) * 64 + 8 * g;
                pa0 = *(const f32x4*)(np);
                pa1 = *(const f32x4*)(np + 4);
                pa2 = *(const f32x4*)(np + 32);
                pa3 = *(const f32x4*)(np + 36);
            }
            if (nrowA + 16 < B) {
                const float* np = x + (nrowA + 16 + c) * 64 + 8 * g;
                pb0 = *(const f32x4*)(np);
                pb1 = *(const f32x4*)(np + 4);
                pb2 = *(const f32x4*)(np + 32);
                pb3 = *(const f32x4*)(np + 36);
            }
        }

        process(curA, qa0, qa1, qa2, qa3);
        if (curA + 16 < B) process(curA + 16, qb0, qb1, qb2, qb3);

        rowA = nrowA;
    }
}

extern "C" void kernel_launch(void* const* d_in, const int* in_sizes, int n_in,
                              void* d_out, int out_size, void* d_ws, size_t ws_size,
                              hipStream_t stream) {
    const float* x   = (const float*)d_in[0];
    const float* W1  = (const float*)d_in[1];
    const float* b1  = (const float*)d_in[2];
    const float* lng = (const float*)d_in[3];
    const float* lnb = (const float*)d_in[4];
    const float* W2  = (const float*)d_in[5];
    const float* b2  = (const float*)d_in[6];
    const float* Wg1 = (const float*)d_in[7];
    const float* bg1 = (const float*)d_in[8];
    const float* Wg2 = (const float*)d_in[9];
    const float* bg2 = (const float*)d_in[10];
    const float* We1 = (const float*)d_in[11];
    const float* be1 = (const float*)d_in[12];
    const float* We2 = (const float*)d_in[13];
    const float* be2 = (const float*)d_in[14];
    const float* Wh  = (const float*)d_in[15];
    const float* bh  = (const float*)d_in[16];
    const float* osc = (const float*)d_in[17];
    float* out = (float*)d_out;

    const int B = in_sizes[0] / 64;
    const int G = 4096;
    const long long per = (long long)G * 128;
    const int niter = (int)((B + per - 1) / per);
    moe_mfma6_kernel<<<dim3(G), dim3(256), 0, stream>>>(
        x, W1, b1, lng, lnb, W2, b2, Wg1, bg1, Wg2, bg2,
        We1, be1, We2, be2, Wh, bh, osc, out, B, niter);
}